// Round 6
// baseline (2487.560 us; speedup 1.0000x reference)
//
#include <hip/hip_runtime.h>

#define BATCH   32768
#define DIM     256
#define NCODES  8192
#define BETA    0.25f
#define EPS     3e-4f     // screen window: grid-tie ulp + 2*delta(bf16 screen) + bf16-tilemin fuzz
#define CAND_CAP 128      // per-row LDS candidate slots (avg ~16; overflow handled inline)

typedef unsigned short ushort_t;
typedef unsigned char  uchar_t;
typedef unsigned long long u64;
typedef __attribute__((ext_vector_type(8))) short bf16x8;
typedef __attribute__((ext_vector_type(4))) float f32x4;

// async global->LDS, 16B per lane; dest = wave-uniform base + lane*16
#define GLOAD16(gp, lp) __builtin_amdgcn_global_load_lds( \
    (const __attribute__((address_space(1))) void*)(gp), \
    (__attribute__((address_space(3))) void*)(lp), 16, 0, 0)

__device__ inline ushort_t f2bf(float f) {  // RNE float->bf16 (no NaN in data)
    union { float f; unsigned u; } v; v.f = f;
    return (ushort_t)((v.u + 0x7FFF + ((v.u >> 16) & 1)) >> 16);
}
__device__ inline ushort_t f2bf_rd(float f) {  // round toward -inf (conservative tilemin)
    union { float f; unsigned u; } v; v.f = f;
    unsigned u = v.u;
    if (f < 0.0f) u += 0xFFFFu;   // magnitude up for negatives => value down
    return (ushort_t)(u >> 16);
}

// ============================================================================
// Kernel A: fused prep. One wave per row (codebook rows then z rows):
// e2[k]/z2[b] row sums-of-squares + bf16 copies eh/zh. Zeroes the loss
// accumulator (d_ws is poisoned 0xAA every launch).
// ============================================================================
__global__ void vq_prep_kernel(const float* __restrict__ z,
                               const float* __restrict__ cb,
                               float* __restrict__ e2, float* __restrict__ z2,
                               ushort_t* __restrict__ eh, ushort_t* __restrict__ zh,
                               float* __restrict__ loss_acc) {
    const int lane = threadIdx.x & 63;
    const int wid  = threadIdx.x >> 6;
    const int item = blockIdx.x * 4 + wid;
    const float* src;
    ushort_t* dst;
    if (item < NCODES) { src = cb + (size_t)item * DIM;            dst = eh + (size_t)item * DIM; }
    else               { src = z  + (size_t)(item - NCODES) * DIM; dst = zh + (size_t)(item - NCODES) * DIM; }
    const float4 v = *(const float4*)(src + lane * 4);
    ushort4 b; b.x = f2bf(v.x); b.y = f2bf(v.y); b.z = f2bf(v.z); b.w = f2bf(v.w);
    *(ushort4*)(dst + lane * 4) = b;
    float s = v.x * v.x + v.y * v.y + v.z * v.z + v.w * v.w;
    #pragma unroll
    for (int off = 32; off > 0; off >>= 1) s += __shfl_down(s, off, 64);
    if (lane == 0) {
        if (item < NCODES) e2[item] = s;
        else               z2[item - NCODES] = s;
    }
    if (blockIdx.x == 0 && threadIdx.x == 0) *loss_acc = 0.0f;
}

// ============================================================================
// Kernel B: MFMA screen, CODE-SPLIT 4x for occupancy (R5: grid 512 = 2
// blocks/CU = 22.8% occ, barrier drains unhidden). Each block: 64 rows x
// 2048 codes (4 tile-groups of 512); grid = 512 x 4 = 2048 blocks -> 4
// resident blocks/CU (LDS 38.9 KB). approx score s = e2[c] - 2*(zh.eh),
// bf16 MFMA fp32-acc. Per (row, 128-code tile): bf16 round-down tile-min
// (layout [row][tile]) + 128-bit mask of codes with s <= tilemin_f32 + EPS
// (masks live in d_out's zq region, overwritten later by the gather).
// ============================================================================
__launch_bounds__(256, 4)
__global__ void vq_screen_kernel(const ushort_t* __restrict__ zh_g,
                                 const ushort_t* __restrict__ eh_g,
                                 const float* __restrict__ e2g,
                                 ushort_t* __restrict__ tilemin_g,
                                 uchar_t* __restrict__ mask_g) {
    __shared__ ushort_t zh_s[64 * 32];    // 4 row-tiles of [16][32]
    __shared__ ushort_t eh_s[512 * 32];   // 32 code-tiles of [16][32]
    __shared__ float    e2_s[512];

    const int t    = threadIdx.x;
    const int w    = t >> 6;        // wave 0..3
    const int lane = t & 63;
    const int c    = lane & 15;     // MFMA col / fragment row
    const int q    = lane >> 4;     // MFMA quad
    const int cg   = blockIdx.x & 3;        // code group (2048 codes)
    const int row0 = (blockIdx.x >> 2) * 64;

    for (int ct2 = 0; ct2 < 4; ++ct2) {
        const int ctg = cg * 4 + ct2;          // global 512-code group 0..15
        __syncthreads();                       // prev epilogue done before e2_s restage
        e2_s[t]       = e2g[ctg * 512 + t];
        e2_s[256 + t] = e2g[ctg * 512 + 256 + t];

        f32x4 acc[4][8];
        #pragma unroll
        for (int i = 0; i < 4; ++i)
            #pragma unroll
            for (int j = 0; j < 8; ++j) acc[i][j] = (f32x4)0.0f;

        for (int kc = 0; kc < 256; kc += 32) {
            __syncthreads();                   // prev chunk's frag reads done
            GLOAD16(zh_g + (size_t)(row0 + w * 16 + (lane >> 2)) * DIM + kc + (lane & 3) * 8,
                    &zh_s[w * 512]);
            #pragma unroll
            for (int s8 = 0; s8 < 8; ++s8) {
                const int c16 = w * 8 + s8;
                GLOAD16(eh_g + (size_t)(ctg * 512 + c16 * 16 + (lane >> 2)) * DIM + kc + (lane & 3) * 8,
                        &eh_s[c16 * 512]);
            }
            __syncthreads();                   // vmcnt(0) drain + visibility

            bf16x8 a[4], b[8];
            #pragma unroll
            for (int i = 0; i < 4; ++i)
                a[i] = *(const bf16x8*)&zh_s[i * 512 + c * 32 + q * 8];
            #pragma unroll
            for (int j = 0; j < 8; ++j)
                b[j] = *(const bf16x8*)&eh_s[(w * 8 + j) * 512 + c * 32 + q * 8];
            #pragma unroll
            for (int i = 0; i < 4; ++i)
                #pragma unroll
                for (int j = 0; j < 8; ++j)
                    acc[i][j] = __builtin_amdgcn_mfma_f32_16x16x32_bf16(a[i], b[j], acc[i][j], 0, 0, 0);
        }

        // epilogue: scores, per-row tile min, mask bits
        float tm[4][4];
        #pragma unroll
        for (int i = 0; i < 4; ++i)
            #pragma unroll
            for (int reg = 0; reg < 4; ++reg) tm[i][reg] = 3.4e38f;
        #pragma unroll
        for (int i = 0; i < 4; ++i)
            #pragma unroll
            for (int j = 0; j < 8; ++j) {
                const float e2v = e2_s[w * 128 + j * 16 + c];
                #pragma unroll
                for (int reg = 0; reg < 4; ++reg) {
                    const float s = fmaf(-2.0f, acc[i][j][reg], e2v);
                    acc[i][j][reg] = s;
                    tm[i][reg] = fminf(tm[i][reg], s);
                }
            }
        #pragma unroll
        for (int st = 1; st < 16; st <<= 1)
            #pragma unroll
            for (int i = 0; i < 4; ++i)
                #pragma unroll
                for (int reg = 0; reg < 4; ++reg)
                    tm[i][reg] = fminf(tm[i][reg], __shfl_xor(tm[i][reg], st, 64));

        const int tile = ctg * 4 + w;
        #pragma unroll
        for (int i = 0; i < 4; ++i)
            #pragma unroll
            for (int reg = 0; reg < 4; ++reg) {
                const int row = row0 + i * 16 + q * 4 + reg;
                const float thr = tm[i][reg] + EPS;
                unsigned m8 = 0;
                #pragma unroll
                for (int j = 0; j < 8; ++j)
                    m8 |= (unsigned)(acc[i][j][reg] <= thr) << j;
                mask_g[(size_t)row * 1024 + tile * 16 + c] = (uchar_t)m8;
                if (c == 0) tilemin_g[(size_t)row * 64 + tile] = f2bf_rd(tm[i][reg]);
            }
    }
}

// ============================================================================
// exact score, bit-identical to R2's verified numerics: ascending-k
// sequential fmaf; S = fl(z2+e2); score = fl(S - 2*acc). Returns
// (score_bits<<32 | code): positive scores => float bits monotone; u64 min
// over candidates => lowest code on exact grid ties.
// ============================================================================
__device__ inline u64 vq_eval(const float* zrow, const float* __restrict__ cb,
                              const float* __restrict__ e2g, float z2v, int code) {
    const float4* z4 = (const float4*)zrow;
    const float4* e4 = (const float4*)(cb + (size_t)code * DIM);
    float acc = 0.0f;
    #pragma unroll 8
    for (int k4 = 0; k4 < DIM / 4; ++k4) {
        const float4 a = z4[k4];
        const float4 b = e4[k4];
        acc = fmaf(a.x, b.x, acc);
        acc = fmaf(a.y, b.y, acc);
        acc = fmaf(a.z, b.z, acc);
        acc = fmaf(a.w, b.w, acc);
    }
    const float S  = z2v + e2g[code];
    const float sc = fmaf(-2.0f, acc, S);
    union { float f; unsigned u; } sb; sb.f = sc;
    return ((u64)sb.u << 32) | (unsigned)code;
}

// ============================================================================
// Kernel C: fused select (replaces R5 candidates+exact; no global atomics,
// no worklist round-trip). ONE WAVE PER ROW (lane = tile): coalesced bf16
// tile-min load, butterfly gmin, active lanes enumerate their tile's mask
// into per-wave LDS slots via prefix scan; then lane = slot evaluates exact
// scores (z row LDS-cached, uniform-address broadcast reads); in-wave u64
// butterfly min picks the winner. >CAND_CAP overflow evaluated inline by
// the emitting lane (min is associative -> order-independent).
// ============================================================================
__global__ void vq_select_kernel(const float* __restrict__ z,
                                 const float* __restrict__ cb,
                                 const float* __restrict__ e2g,
                                 const float* __restrict__ z2g,
                                 const ushort_t* __restrict__ tilemin_g,
                                 const uchar_t* __restrict__ mask_g,
                                 float* __restrict__ idx_f,
                                 int* __restrict__ idx_i) {
    __shared__ float    zrow_s[4][DIM];
    __shared__ ushort_t cand_s[4][CAND_CAP];

    const int lane = threadIdx.x & 63;
    const int w    = threadIdx.x >> 6;
    const int row  = blockIdx.x * 4 + w;

    // stage z row (float4/lane); visible to other lanes after barrier #1
    *(float4*)&zrow_s[w][lane * 4] = *(const float4*)(z + (size_t)row * DIM + lane * 4);

    union { unsigned u; float f; } tv;
    tv.u = ((unsigned)tilemin_g[(size_t)row * 64 + lane]) << 16;
    const float tm = tv.f;
    float gmin = tm;
    #pragma unroll
    for (int d = 32; d > 0; d >>= 1) gmin = fminf(gmin, __shfl_xor(gmin, d, 64));
    const float thr = gmin + EPS;

    u64 m0 = 0, m1 = 0;
    if (tm <= thr) {
        const uchar_t* mb = mask_g + (size_t)row * 1024 + lane * 16;
        m0 = *(const u64*)(mb);
        m1 = *(const u64*)(mb + 8);
    }
    const unsigned cnt = __popcll(m0) + __popcll(m1);
    unsigned inc = cnt;
    #pragma unroll
    for (int d = 1; d < 64; d <<= 1) {
        const unsigned o = __shfl_up(inc, d, 64);
        if (lane >= d) inc += o;
    }
    const unsigned excl  = inc - cnt;
    const unsigned total = __shfl(inc, 63, 64);
    const float z2v = z2g[row];
    u64 best = ~0ull;

    __syncthreads();   // barrier #1: zrow_s visible (overflow eval below reads it)

    // emit candidates (bit p in m0/m1: byte c = p>>3, bit j = p&7 -> code j*16+c)
    unsigned slot = excl;
    while (m0) {
        const int p = __builtin_ctzll(m0); m0 &= m0 - 1;
        const unsigned code = lane * 128 + (p & 7) * 16 + (p >> 3);
        if (slot < CAND_CAP) cand_s[w][slot] = (ushort_t)code;
        else best = min(best, vq_eval(zrow_s[w], cb, e2g, z2v, (int)code));
        ++slot;
    }
    while (m1) {
        const int p = __builtin_ctzll(m1); m1 &= m1 - 1;
        const unsigned code = lane * 128 + (p & 7) * 16 + 8 + (p >> 3);
        if (slot < CAND_CAP) cand_s[w][slot] = (ushort_t)code;
        else best = min(best, vq_eval(zrow_s[w], cb, e2g, z2v, (int)code));
        ++slot;
    }

    __syncthreads();   // barrier #2: cand_s visible

    const int n = (int)(total < CAND_CAP ? total : CAND_CAP);
    for (int s = lane; s < n; s += 64)
        best = min(best, vq_eval(zrow_s[w], cb, e2g, z2v, (int)cand_s[w][s]));

    #pragma unroll
    for (int d = 32; d > 0; d >>= 1) {
        const u64 o = (u64)__shfl_xor((unsigned long long)best, d, 64);
        best = min(best, o);
    }
    if (lane == 0) {
        const int k = (int)(best & (u64)(NCODES - 1));
        idx_f[row] = (float)k;
        idx_i[row] = k;
    }
}

// ============================================================================
// Kernel D: gather + ST + loss. z_q_st = fl(z_e + fl(z_q - z_e)).
// ============================================================================
__global__ void vq_gather_loss_kernel(const float* __restrict__ z,
                                      const float* __restrict__ cb,
                                      const int* __restrict__ idx_i,
                                      float* __restrict__ zq_out,
                                      float* __restrict__ loss_acc) {
    const int lane = threadIdx.x & 63;
    const int wid  = threadIdx.x >> 6;
    const int row  = blockIdx.x * 4 + wid;
    const int k = idx_i[row];
    const float4 e  = *(const float4*)(cb + (size_t)k * DIM + lane * 4);
    const float4 zv = *(const float4*)(z + (size_t)row * DIM + lane * 4);
    const float dx = e.x - zv.x, dy = e.y - zv.y, dz = e.z - zv.z, dw = e.w - zv.w;
    float4 o;
    o.x = zv.x + dx; o.y = zv.y + dy; o.z = zv.z + dz; o.w = zv.w + dw;
    *(float4*)(zq_out + (size_t)row * DIM + lane * 4) = o;
    float s = dx * dx + dy * dy + dz * dz + dw * dw;
    #pragma unroll
    for (int off = 32; off > 0; off >>= 1) s += __shfl_down(s, off, 64);
    __shared__ float wsum[4];
    if (lane == 0) wsum[wid] = s;
    __syncthreads();
    if (threadIdx.x == 0)
        atomicAdd(loss_acc, wsum[0] + wsum[1] + wsum[2] + wsum[3]);
}

// ============================================================================
// Kernel E: finalize scalars.
// ============================================================================
__global__ void vq_finalize_kernel(const float* __restrict__ loss_acc,
                                   float* __restrict__ out_losses) {
    const float mean = *loss_acc * (1.0f / (float)(BATCH * DIM));  // /2^23 exact
    out_losses[0] = mean + BETA * mean;    // vq_loss
    out_losses[1] = mean;                  // cb_loss
    out_losses[2] = mean;                  // commit_loss
}

// ============================================================================
extern "C" void kernel_launch(void* const* d_in, const int* in_sizes, int n_in,
                              void* d_out, int out_size, void* d_ws, size_t ws_size,
                              hipStream_t stream) {
    const float* z  = (const float*)d_in[0];   // [32768, 256] fp32
    const float* cb = (const float*)d_in[1];   // [8192, 256]  fp32

    float* out    = (float*)d_out;
    float* zq     = out;                                   // [32768*256]
    float* idx_f  = out + (size_t)BATCH * DIM;             // [32768]
    float* losses = out + (size_t)BATCH * DIM + BATCH;     // [3]
    uchar_t* mask = (uchar_t*)d_out;                       // zq region reused: 1 KB/row

    // ws layout (~20.6 MB): ctrl[256 f] | e2 | z2 | tilemin(u16) | idxi(i32)
    //                       | zh(u16) | eh(u16)
    float*    ws        = (float*)d_ws;
    float*    loss_acc  = ws;                                       // [0]
    float*    e2        = ws + 256;                                 // 8192 f
    float*    z2        = e2 + NCODES;                              // 32768 f
    ushort_t* tilemin   = (ushort_t*)(z2 + BATCH);                  // 32768*64 u16
    int*      idxi      = (int*)(tilemin + (size_t)BATCH * 64);     // 32768 i32
    ushort_t* zh        = (ushort_t*)(idxi + BATCH);                // 32768*256 u16
    ushort_t* eh        = zh + (size_t)BATCH * DIM;                 // 8192*256 u16

    vq_prep_kernel<<<(NCODES + BATCH) / 4, 256, 0, stream>>>(z, cb, e2, z2, eh, zh, loss_acc);
    vq_screen_kernel<<<(BATCH / 64) * 4, 256, 0, stream>>>(zh, eh, e2, tilemin, mask);
    vq_select_kernel<<<BATCH / 4, 256, 0, stream>>>(z, cb, e2, z2, tilemin, mask, idx_f, idxi);
    vq_gather_loss_kernel<<<BATCH / 4, 256, 0, stream>>>(z, cb, idxi, zq, loss_acc);
    vq_finalize_kernel<<<1, 1, 0, stream>>>(loss_acc, losses);
}

// Round 7
// 547.328 us; speedup vs baseline: 4.5449x; 4.5449x over previous
//
#include <hip/hip_runtime.h>

#define BATCH   32768
#define DIM     256
#define NCODES  8192
#define BETA    0.25f
#define EPS     3e-4f     // screen window: grid-tie ulp + 2*delta(bf16 screen) + bf16-tilemin fuzz
#define CAND_CAP 128      // per-row LDS candidate slots (avg ~16; overflow handled inline)

typedef unsigned short ushort_t;
typedef unsigned char  uchar_t;
typedef unsigned long long u64;
typedef __attribute__((ext_vector_type(8))) short bf16x8;
typedef __attribute__((ext_vector_type(4))) float f32x4;

// async global->LDS, 16B per lane; dest = wave-uniform base + lane*16
#define GLOAD16(gp, lp) __builtin_amdgcn_global_load_lds( \
    (const __attribute__((address_space(1))) void*)(gp), \
    (__attribute__((address_space(3))) void*)(lp), 16, 0, 0)

__device__ inline ushort_t f2bf(float f) {  // RNE float->bf16 (no NaN in data)
    union { float f; unsigned u; } v; v.f = f;
    return (ushort_t)((v.u + 0x7FFF + ((v.u >> 16) & 1)) >> 16);
}
__device__ inline ushort_t f2bf_rd(float f) {  // round toward -inf (conservative tilemin)
    union { float f; unsigned u; } v; v.f = f;
    unsigned u = v.u;
    if (f < 0.0f) u += 0xFFFFu;   // magnitude up for negatives => value down
    return (ushort_t)(u >> 16);
}

// ============================================================================
// Kernel A: fused prep. One wave per row (codebook rows then z rows):
// e2[k]/z2[b] row sums-of-squares + bf16 copies eh/zh. Zeroes the loss
// accumulator (d_ws is poisoned 0xAA every launch).
// ============================================================================
__global__ void vq_prep_kernel(const float* __restrict__ z,
                               const float* __restrict__ cb,
                               float* __restrict__ e2, float* __restrict__ z2,
                               ushort_t* __restrict__ eh, ushort_t* __restrict__ zh,
                               float* __restrict__ loss_acc) {
    const int lane = threadIdx.x & 63;
    const int wid  = threadIdx.x >> 6;
    const int item = blockIdx.x * 4 + wid;
    const float* src;
    ushort_t* dst;
    if (item < NCODES) { src = cb + (size_t)item * DIM;            dst = eh + (size_t)item * DIM; }
    else               { src = z  + (size_t)(item - NCODES) * DIM; dst = zh + (size_t)(item - NCODES) * DIM; }
    const float4 v = *(const float4*)(src + lane * 4);
    ushort4 b; b.x = f2bf(v.x); b.y = f2bf(v.y); b.z = f2bf(v.z); b.w = f2bf(v.w);
    *(ushort4*)(dst + lane * 4) = b;
    float s = v.x * v.x + v.y * v.y + v.z * v.z + v.w * v.w;
    #pragma unroll
    for (int off = 32; off > 0; off >>= 1) s += __shfl_down(s, off, 64);
    if (lane == 0) {
        if (item < NCODES) e2[item] = s;
        else               z2[item - NCODES] = s;
    }
    if (blockIdx.x == 0 && threadIdx.x == 0) *loss_acc = 0.0f;
}

// ============================================================================
// Kernel B: MFMA screen, 4x code-split grid (2048 blocks) for residency.
// __launch_bounds__(256,2): VGPR=128, NO SPILL. (R6's (256,4) forced
// VGPR=64 -> accumulator spill -> 8.4 GB scratch traffic, 7.4x regression.
// At VGPR=128 the HW cap is 16 waves/CU = 4 blocks/CU, same as the
// LDS cap 160/38.9 -> launch bounds 2 already permits full residency.)
// Each block: 64 rows x 2048 codes (4 tile-groups of 512).
// approx score s = e2[c] - 2*(zh.eh), bf16 MFMA fp32-acc. Per (row,
// 128-code tile): bf16 round-down tile-min (layout [row][tile]) + 128-bit
// mask of codes with s <= tilemin_f32 + EPS (masks live in d_out's zq
// region, overwritten later by the gather).
// ============================================================================
__launch_bounds__(256, 2)
__global__ void vq_screen_kernel(const ushort_t* __restrict__ zh_g,
                                 const ushort_t* __restrict__ eh_g,
                                 const float* __restrict__ e2g,
                                 ushort_t* __restrict__ tilemin_g,
                                 uchar_t* __restrict__ mask_g) {
    __shared__ ushort_t zh_s[64 * 32];    // 4 row-tiles of [16][32]
    __shared__ ushort_t eh_s[512 * 32];   // 32 code-tiles of [16][32]
    __shared__ float    e2_s[512];

    const int t    = threadIdx.x;
    const int w    = t >> 6;        // wave 0..3
    const int lane = t & 63;
    const int c    = lane & 15;     // MFMA col / fragment row
    const int q    = lane >> 4;     // MFMA quad
    const int cg   = blockIdx.x & 3;        // code group (2048 codes)
    const int row0 = (blockIdx.x >> 2) * 64;

    for (int ct2 = 0; ct2 < 4; ++ct2) {
        const int ctg = cg * 4 + ct2;          // global 512-code group 0..15
        __syncthreads();                       // prev epilogue done before e2_s restage
        e2_s[t]       = e2g[ctg * 512 + t];
        e2_s[256 + t] = e2g[ctg * 512 + 256 + t];

        f32x4 acc[4][8];
        #pragma unroll
        for (int i = 0; i < 4; ++i)
            #pragma unroll
            for (int j = 0; j < 8; ++j) acc[i][j] = (f32x4)0.0f;

        for (int kc = 0; kc < 256; kc += 32) {
            __syncthreads();                   // prev chunk's frag reads done
            GLOAD16(zh_g + (size_t)(row0 + w * 16 + (lane >> 2)) * DIM + kc + (lane & 3) * 8,
                    &zh_s[w * 512]);
            #pragma unroll
            for (int s8 = 0; s8 < 8; ++s8) {
                const int c16 = w * 8 + s8;
                GLOAD16(eh_g + (size_t)(ctg * 512 + c16 * 16 + (lane >> 2)) * DIM + kc + (lane & 3) * 8,
                        &eh_s[c16 * 512]);
            }
            __syncthreads();                   // vmcnt(0) drain + visibility

            bf16x8 a[4], b[8];
            #pragma unroll
            for (int i = 0; i < 4; ++i)
                a[i] = *(const bf16x8*)&zh_s[i * 512 + c * 32 + q * 8];
            #pragma unroll
            for (int j = 0; j < 8; ++j)
                b[j] = *(const bf16x8*)&eh_s[(w * 8 + j) * 512 + c * 32 + q * 8];
            #pragma unroll
            for (int i = 0; i < 4; ++i)
                #pragma unroll
                for (int j = 0; j < 8; ++j)
                    acc[i][j] = __builtin_amdgcn_mfma_f32_16x16x32_bf16(a[i], b[j], acc[i][j], 0, 0, 0);
        }

        // epilogue: scores, per-row tile min, mask bits
        float tm[4][4];
        #pragma unroll
        for (int i = 0; i < 4; ++i)
            #pragma unroll
            for (int reg = 0; reg < 4; ++reg) tm[i][reg] = 3.4e38f;
        #pragma unroll
        for (int i = 0; i < 4; ++i)
            #pragma unroll
            for (int j = 0; j < 8; ++j) {
                const float e2v = e2_s[w * 128 + j * 16 + c];
                #pragma unroll
                for (int reg = 0; reg < 4; ++reg) {
                    const float s = fmaf(-2.0f, acc[i][j][reg], e2v);
                    acc[i][j][reg] = s;
                    tm[i][reg] = fminf(tm[i][reg], s);
                }
            }
        #pragma unroll
        for (int st = 1; st < 16; st <<= 1)
            #pragma unroll
            for (int i = 0; i < 4; ++i)
                #pragma unroll
                for (int reg = 0; reg < 4; ++reg)
                    tm[i][reg] = fminf(tm[i][reg], __shfl_xor(tm[i][reg], st, 64));

        const int tile = ctg * 4 + w;
        #pragma unroll
        for (int i = 0; i < 4; ++i)
            #pragma unroll
            for (int reg = 0; reg < 4; ++reg) {
                const int row = row0 + i * 16 + q * 4 + reg;
                const float thr = tm[i][reg] + EPS;
                unsigned m8 = 0;
                #pragma unroll
                for (int j = 0; j < 8; ++j)
                    m8 |= (unsigned)(acc[i][j][reg] <= thr) << j;
                mask_g[(size_t)row * 1024 + tile * 16 + c] = (uchar_t)m8;
                if (c == 0) tilemin_g[(size_t)row * 64 + tile] = f2bf_rd(tm[i][reg]);
            }
    }
}

// ============================================================================
// exact score, bit-identical to R2's verified numerics: ascending-k
// sequential fmaf; S = fl(z2+e2); score = fl(S - 2*acc). Returns
// (score_bits<<32 | code): positive scores => float bits monotone; u64 min
// over candidates => lowest code on exact grid ties.
// ============================================================================
__device__ inline u64 vq_eval(const float* zrow, const float* __restrict__ cb,
                              const float* __restrict__ e2g, float z2v, int code) {
    const float4* z4 = (const float4*)zrow;
    const float4* e4 = (const float4*)(cb + (size_t)code * DIM);
    float acc = 0.0f;
    #pragma unroll 8
    for (int k4 = 0; k4 < DIM / 4; ++k4) {
        const float4 a = z4[k4];
        const float4 b = e4[k4];
        acc = fmaf(a.x, b.x, acc);
        acc = fmaf(a.y, b.y, acc);
        acc = fmaf(a.z, b.z, acc);
        acc = fmaf(a.w, b.w, acc);
    }
    const float S  = z2v + e2g[code];
    const float sc = fmaf(-2.0f, acc, S);
    union { float f; unsigned u; } sb; sb.f = sc;
    return ((u64)sb.u << 32) | (unsigned)code;
}

// ============================================================================
// Kernel C: fused select (no global atomics, no worklist round-trip).
// ONE WAVE PER ROW (lane = tile): coalesced bf16 tile-min load, butterfly
// gmin, active lanes enumerate their tile's mask into per-wave LDS slots
// via prefix scan; then lane = slot evaluates exact scores (z row
// LDS-cached); in-wave u64 butterfly min picks the winner. >CAND_CAP
// overflow evaluated inline by the emitting lane (min is associative).
// ============================================================================
__global__ void vq_select_kernel(const float* __restrict__ z,
                                 const float* __restrict__ cb,
                                 const float* __restrict__ e2g,
                                 const float* __restrict__ z2g,
                                 const ushort_t* __restrict__ tilemin_g,
                                 const uchar_t* __restrict__ mask_g,
                                 float* __restrict__ idx_f,
                                 int* __restrict__ idx_i) {
    __shared__ float    zrow_s[4][DIM];
    __shared__ ushort_t cand_s[4][CAND_CAP];

    const int lane = threadIdx.x & 63;
    const int w    = threadIdx.x >> 6;
    const int row  = blockIdx.x * 4 + w;

    // stage z row (float4/lane); visible to other lanes after barrier #1
    *(float4*)&zrow_s[w][lane * 4] = *(const float4*)(z + (size_t)row * DIM + lane * 4);

    union { unsigned u; float f; } tv;
    tv.u = ((unsigned)tilemin_g[(size_t)row * 64 + lane]) << 16;
    const float tm = tv.f;
    float gmin = tm;
    #pragma unroll
    for (int d = 32; d > 0; d >>= 1) gmin = fminf(gmin, __shfl_xor(gmin, d, 64));
    const float thr = gmin + EPS;

    u64 m0 = 0, m1 = 0;
    if (tm <= thr) {
        const uchar_t* mb = mask_g + (size_t)row * 1024 + lane * 16;
        m0 = *(const u64*)(mb);
        m1 = *(const u64*)(mb + 8);
    }
    const unsigned cnt = __popcll(m0) + __popcll(m1);
    unsigned inc = cnt;
    #pragma unroll
    for (int d = 1; d < 64; d <<= 1) {
        const unsigned o = __shfl_up(inc, d, 64);
        if (lane >= d) inc += o;
    }
    const unsigned excl  = inc - cnt;
    const unsigned total = __shfl(inc, 63, 64);
    const float z2v = z2g[row];
    u64 best = ~0ull;

    __syncthreads();   // barrier #1: zrow_s visible (overflow eval below reads it)

    // emit candidates (bit p in m0/m1: byte c = p>>3, bit j = p&7 -> code j*16+c)
    unsigned slot = excl;
    while (m0) {
        const int p = __builtin_ctzll(m0); m0 &= m0 - 1;
        const unsigned code = lane * 128 + (p & 7) * 16 + (p >> 3);
        if (slot < CAND_CAP) cand_s[w][slot] = (ushort_t)code;
        else best = min(best, vq_eval(zrow_s[w], cb, e2g, z2v, (int)code));
        ++slot;
    }
    while (m1) {
        const int p = __builtin_ctzll(m1); m1 &= m1 - 1;
        const unsigned code = lane * 128 + (p & 7) * 16 + 8 + (p >> 3);
        if (slot < CAND_CAP) cand_s[w][slot] = (ushort_t)code;
        else best = min(best, vq_eval(zrow_s[w], cb, e2g, z2v, (int)code));
        ++slot;
    }

    __syncthreads();   // barrier #2: cand_s visible

    const int n = (int)(total < CAND_CAP ? total : CAND_CAP);
    for (int s = lane; s < n; s += 64)
        best = min(best, vq_eval(zrow_s[w], cb, e2g, z2v, (int)cand_s[w][s]));

    #pragma unroll
    for (int d = 32; d > 0; d >>= 1) {
        const u64 o = (u64)__shfl_xor((unsigned long long)best, d, 64);
        best = min(best, o);
    }
    if (lane == 0) {
        const int k = (int)(best & (u64)(NCODES - 1));
        idx_f[row] = (float)k;
        idx_i[row] = k;
    }
}

// ============================================================================
// Kernel D: gather + ST + loss. z_q_st = fl(z_e + fl(z_q - z_e)).
// ============================================================================
__global__ void vq_gather_loss_kernel(const float* __restrict__ z,
                                      const float* __restrict__ cb,
                                      const int* __restrict__ idx_i,
                                      float* __restrict__ zq_out,
                                      float* __restrict__ loss_acc) {
    const int lane = threadIdx.x & 63;
    const int wid  = threadIdx.x >> 6;
    const int row  = blockIdx.x * 4 + wid;
    const int k = idx_i[row];
    const float4 e  = *(const float4*)(cb + (size_t)k * DIM + lane * 4);
    const float4 zv = *(const float4*)(z + (size_t)row * DIM + lane * 4);
    const float dx = e.x - zv.x, dy = e.y - zv.y, dz = e.z - zv.z, dw = e.w - zv.w;
    float4 o;
    o.x = zv.x + dx; o.y = zv.y + dy; o.z = zv.z + dz; o.w = zv.w + dw;
    *(float4*)(zq_out + (size_t)row * DIM + lane * 4) = o;
    float s = dx * dx + dy * dy + dz * dz + dw * dw;
    #pragma unroll
    for (int off = 32; off > 0; off >>= 1) s += __shfl_down(s, off, 64);
    __shared__ float wsum[4];
    if (lane == 0) wsum[wid] = s;
    __syncthreads();
    if (threadIdx.x == 0)
        atomicAdd(loss_acc, wsum[0] + wsum[1] + wsum[2] + wsum[3]);
}

// ============================================================================
// Kernel E: finalize scalars.
// ============================================================================
__global__ void vq_finalize_kernel(const float* __restrict__ loss_acc,
                                   float* __restrict__ out_losses) {
    const float mean = *loss_acc * (1.0f / (float)(BATCH * DIM));  // /2^23 exact
    out_losses[0] = mean + BETA * mean;    // vq_loss
    out_losses[1] = mean;                  // cb_loss
    out_losses[2] = mean;                  // commit_loss
}

// ============================================================================
extern "C" void kernel_launch(void* const* d_in, const int* in_sizes, int n_in,
                              void* d_out, int out_size, void* d_ws, size_t ws_size,
                              hipStream_t stream) {
    const float* z  = (const float*)d_in[0];   // [32768, 256] fp32
    const float* cb = (const float*)d_in[1];   // [8192, 256]  fp32

    float* out    = (float*)d_out;
    float* zq     = out;                                   // [32768*256]
    float* idx_f  = out + (size_t)BATCH * DIM;             // [32768]
    float* losses = out + (size_t)BATCH * DIM + BATCH;     // [3]
    uchar_t* mask = (uchar_t*)d_out;                       // zq region reused: 1 KB/row

    // ws layout (~20.6 MB): ctrl[256 f] | e2 | z2 | tilemin(u16) | idxi(i32)
    //                       | zh(u16) | eh(u16)
    float*    ws        = (float*)d_ws;
    float*    loss_acc  = ws;                                       // [0]
    float*    e2        = ws + 256;                                 // 8192 f
    float*    z2        = e2 + NCODES;                              // 32768 f
    ushort_t* tilemin   = (ushort_t*)(z2 + BATCH);                  // 32768*64 u16
    int*      idxi      = (int*)(tilemin + (size_t)BATCH * 64);     // 32768 i32
    ushort_t* zh        = (ushort_t*)(idxi + BATCH);                // 32768*256 u16
    ushort_t* eh        = zh + (size_t)BATCH * DIM;                 // 8192*256 u16

    vq_prep_kernel<<<(NCODES + BATCH) / 4, 256, 0, stream>>>(z, cb, e2, z2, eh, zh, loss_acc);
    vq_screen_kernel<<<(BATCH / 64) * 4, 256, 0, stream>>>(zh, eh, e2, tilemin, mask);
    vq_select_kernel<<<BATCH / 4, 256, 0, stream>>>(z, cb, e2, z2, tilemin, mask, idx_f, idxi);
    vq_gather_loss_kernel<<<BATCH / 4, 256, 0, stream>>>(z, cb, idxi, zq, loss_acc);
    vq_finalize_kernel<<<1, 1, 0, stream>>>(loss_acc, losses);
}

// Round 8
// 498.973 us; speedup vs baseline: 4.9854x; 1.0969x over previous
//
#include <hip/hip_runtime.h>

#define BATCH   32768
#define DIM     256
#define NCODES  8192
#define BETA    0.25f
#define EPS     3e-4f     // screen window: grid-tie ulp + 2*delta(bf16 screen) + bf16-tilemin fuzz
#define CAND_CAP 128      // per-row LDS candidate slots (avg ~16; overflow handled inline)

typedef unsigned short ushort_t;
typedef unsigned char  uchar_t;
typedef unsigned long long u64;
typedef __attribute__((ext_vector_type(8))) short bf16x8;
typedef __attribute__((ext_vector_type(4))) float f32x4;

// async global->LDS, 16B per lane; dest = wave-uniform base + lane*16
#define GLOAD16(gp, lp) __builtin_amdgcn_global_load_lds( \
    (const __attribute__((address_space(1))) void*)(gp), \
    (__attribute__((address_space(3))) void*)(lp), 16, 0, 0)

__device__ inline ushort_t f2bf(float f) {  // RNE float->bf16 (no NaN in data)
    union { float f; unsigned u; } v; v.f = f;
    return (ushort_t)((v.u + 0x7FFF + ((v.u >> 16) & 1)) >> 16);
}
__device__ inline ushort_t f2bf_rd(float f) {  // round toward -inf (conservative tilemin)
    union { float f; unsigned u; } v; v.f = f;
    unsigned u = v.u;
    if (f < 0.0f) u += 0xFFFFu;   // magnitude up for negatives => value down
    return (ushort_t)(u >> 16);
}

// ============================================================================
// Kernel A: fused prep. One wave per row (codebook rows then z rows):
// e2[k]/z2[b] row sums-of-squares + bf16 copies eh/zh. Zeroes the loss
// accumulator (d_ws is poisoned 0xAA every launch).
// ============================================================================
__global__ void vq_prep_kernel(const float* __restrict__ z,
                               const float* __restrict__ cb,
                               float* __restrict__ e2, float* __restrict__ z2,
                               ushort_t* __restrict__ eh, ushort_t* __restrict__ zh,
                               float* __restrict__ loss_acc) {
    const int lane = threadIdx.x & 63;
    const int wid  = threadIdx.x >> 6;
    const int item = blockIdx.x * 4 + wid;
    const float* src;
    ushort_t* dst;
    if (item < NCODES) { src = cb + (size_t)item * DIM;            dst = eh + (size_t)item * DIM; }
    else               { src = z  + (size_t)(item - NCODES) * DIM; dst = zh + (size_t)(item - NCODES) * DIM; }
    const float4 v = *(const float4*)(src + lane * 4);
    ushort4 b; b.x = f2bf(v.x); b.y = f2bf(v.y); b.z = f2bf(v.z); b.w = f2bf(v.w);
    *(ushort4*)(dst + lane * 4) = b;
    float s = v.x * v.x + v.y * v.y + v.z * v.z + v.w * v.w;
    #pragma unroll
    for (int off = 32; off > 0; off >>= 1) s += __shfl_down(s, off, 64);
    if (lane == 0) {
        if (item < NCODES) e2[item] = s;
        else               z2[item - NCODES] = s;
    }
    if (blockIdx.x == 0 && threadIdx.x == 0) *loss_acc = 0.0f;
}

// ============================================================================
// Kernel B: MFMA screen with EXPLICIT DMA PIPELINE.
// Register math (R5-R7 lesson): acc[4][8]xf32x4 = 128 AGPR + 128 VGPR = 256
// regs/wave (unified file) -> hard cap 2 waves/SIMD = 2 blocks/CU. R6 proved
// forcing 4 spills 8.4 GB of scratch. So occupancy is FIXED at 2 blocks/CU;
// LDS is free (39/80 KB) -> double-buffer zh/eh (74 KB) and pipeline:
// flat 128-chunk loop (16 ct-groups x 8 kc), ONE barrier per chunk, chunk
// n+1's global_load_lds issued right after barrier n BEFORE chunk n's
// MFMA -> the vmcnt(0) drain at barrier n+1 waits on DMA that overlapped a
// full chunk of compute. Hazards: buf[(n+1)&1] readers (chunk n-1) finished
// before barrier n; reads of buf[n&1] happen between barriers n and n+1. OK.
// e2 now read directly from global in the epilogue (removes the 8-way-
// conflicted e2_s reads + one barrier pair). Grid: 512 = exactly 2/CU.
// Outputs unchanged: bf16 round-down tile-min [row][tile] + 128-bit mask of
// codes with s <= tilemin_f32 + EPS (masks in d_out's zq region).
// ============================================================================
__launch_bounds__(256, 2)
__global__ void vq_screen_kernel(const ushort_t* __restrict__ zh_g,
                                 const ushort_t* __restrict__ eh_g,
                                 const float* __restrict__ e2g,
                                 ushort_t* __restrict__ tilemin_g,
                                 uchar_t* __restrict__ mask_g) {
    __shared__ ushort_t zh_s[2][64 * 32];    // dbuf: 4 row-tiles of [16][32]
    __shared__ ushort_t eh_s[2][512 * 32];   // dbuf: 32 code-tiles of [16][32]

    const int t    = threadIdx.x;
    const int w    = t >> 6;        // wave 0..3
    const int lane = t & 63;
    const int c    = lane & 15;     // MFMA col / fragment row
    const int q    = lane >> 4;     // MFMA quad
    const int row0 = blockIdx.x * 64;

    // per-lane global base offsets (elements)
    const size_t zh_base = (size_t)(row0 + w * 16 + (lane >> 2)) * DIM + (lane & 3) * 8;
    const size_t eh_base = (size_t)((lane >> 2)) * DIM + (lane & 3) * 8;  // + (ct*512+c16*16)*DIM + kc

    // stage chunk n (ct = n>>3, kc = (n&7)*32) into buffer b
    #define STAGE(n_, b_) do {                                              \
        const int ct_ = (n_) >> 3;                                          \
        const int kc_ = ((n_) & 7) * 32;                                    \
        GLOAD16(zh_g + zh_base + kc_, &zh_s[b_][w * 512]);                  \
        _Pragma("unroll")                                                   \
        for (int s8_ = 0; s8_ < 8; ++s8_) {                                 \
            const int c16_ = w * 8 + s8_;                                   \
            GLOAD16(eh_g + eh_base + (size_t)(ct_ * 512 + c16_ * 16) * DIM + kc_, \
                    &eh_s[b_][c16_ * 512]);                                 \
        }                                                                   \
    } while (0)

    STAGE(0, 0);

    f32x4 acc[4][8];
    for (int n = 0; n < 128; ++n) {
        const int kc_i = n & 7;
        if (kc_i == 0) {
            #pragma unroll
            for (int i = 0; i < 4; ++i)
                #pragma unroll
                for (int j = 0; j < 8; ++j) acc[i][j] = (f32x4)0.0f;
        }
        __syncthreads();               // drains own GLOADs (chunk n DMA complete)
        if (n < 127) STAGE(n + 1, (n + 1) & 1);
        const int b = n & 1;

        bf16x8 a[4], bfr[8];
        #pragma unroll
        for (int i = 0; i < 4; ++i)
            a[i] = *(const bf16x8*)&zh_s[b][i * 512 + c * 32 + q * 8];
        #pragma unroll
        for (int j = 0; j < 8; ++j)
            bfr[j] = *(const bf16x8*)&eh_s[b][(w * 8 + j) * 512 + c * 32 + q * 8];
        #pragma unroll
        for (int i = 0; i < 4; ++i)
            #pragma unroll
            for (int j = 0; j < 8; ++j)
                acc[i][j] = __builtin_amdgcn_mfma_f32_16x16x32_bf16(a[i], bfr[j], acc[i][j], 0, 0, 0);

        if (kc_i == 7) {
            // epilogue for ct group: scores, per-row tile min, mask bits.
            const int ct = n >> 3;
            float e2v[8];
            #pragma unroll
            for (int j = 0; j < 8; ++j) e2v[j] = e2g[ct * 512 + w * 128 + j * 16 + c];

            float tm[4][4];
            #pragma unroll
            for (int i = 0; i < 4; ++i)
                #pragma unroll
                for (int reg = 0; reg < 4; ++reg) tm[i][reg] = 3.4e38f;
            #pragma unroll
            for (int i = 0; i < 4; ++i)
                #pragma unroll
                for (int j = 0; j < 8; ++j)
                    #pragma unroll
                    for (int reg = 0; reg < 4; ++reg) {
                        const float s = fmaf(-2.0f, acc[i][j][reg], e2v[j]);
                        acc[i][j][reg] = s;
                        tm[i][reg] = fminf(tm[i][reg], s);
                    }
            #pragma unroll
            for (int st = 1; st < 16; st <<= 1)
                #pragma unroll
                for (int i = 0; i < 4; ++i)
                    #pragma unroll
                    for (int reg = 0; reg < 4; ++reg)
                        tm[i][reg] = fminf(tm[i][reg], __shfl_xor(tm[i][reg], st, 64));

            const int tile = ct * 4 + w;
            #pragma unroll
            for (int i = 0; i < 4; ++i)
                #pragma unroll
                for (int reg = 0; reg < 4; ++reg) {
                    const int row = row0 + i * 16 + q * 4 + reg;
                    const float thr = tm[i][reg] + EPS;
                    unsigned m8 = 0;
                    #pragma unroll
                    for (int j = 0; j < 8; ++j)
                        m8 |= (unsigned)(acc[i][j][reg] <= thr) << j;
                    mask_g[(size_t)row * 1024 + tile * 16 + c] = (uchar_t)m8;
                    if (c == 0) tilemin_g[(size_t)row * 64 + tile] = f2bf_rd(tm[i][reg]);
                }
        }
    }
    #undef STAGE
}

// ============================================================================
// exact score, bit-identical to R2's verified numerics: ascending-k
// sequential fmaf; S = fl(z2+e2); score = fl(S - 2*acc). Returns
// (score_bits<<32 | code): positive scores => float bits monotone; u64 min
// over candidates => lowest code on exact grid ties.
// ============================================================================
__device__ inline u64 vq_eval(const float* zrow, const float* __restrict__ cb,
                              const float* __restrict__ e2g, float z2v, int code) {
    const float4* z4 = (const float4*)zrow;
    const float4* e4 = (const float4*)(cb + (size_t)code * DIM);
    float acc = 0.0f;
    #pragma unroll 8
    for (int k4 = 0; k4 < DIM / 4; ++k4) {
        const float4 a = z4[k4];
        const float4 b = e4[k4];
        acc = fmaf(a.x, b.x, acc);
        acc = fmaf(a.y, b.y, acc);
        acc = fmaf(a.z, b.z, acc);
        acc = fmaf(a.w, b.w, acc);
    }
    const float S  = z2v + e2g[code];
    const float sc = fmaf(-2.0f, acc, S);
    union { float f; unsigned u; } sb; sb.f = sc;
    return ((u64)sb.u << 32) | (unsigned)code;
}

// ============================================================================
// Kernel C: fused select (no global atomics, no worklist round-trip).
// ONE WAVE PER ROW (lane = tile): coalesced bf16 tile-min load, butterfly
// gmin, active lanes enumerate their tile's mask into per-wave LDS slots
// via prefix scan; then lane = slot evaluates exact scores (z row
// LDS-cached); in-wave u64 butterfly min picks the winner. >CAND_CAP
// overflow evaluated inline by the emitting lane (min is associative).
// ============================================================================
__global__ void vq_select_kernel(const float* __restrict__ z,
                                 const float* __restrict__ cb,
                                 const float* __restrict__ e2g,
                                 const float* __restrict__ z2g,
                                 const ushort_t* __restrict__ tilemin_g,
                                 const uchar_t* __restrict__ mask_g,
                                 float* __restrict__ idx_f,
                                 int* __restrict__ idx_i) {
    __shared__ float    zrow_s[4][DIM];
    __shared__ ushort_t cand_s[4][CAND_CAP];

    const int lane = threadIdx.x & 63;
    const int w    = threadIdx.x >> 6;
    const int row  = blockIdx.x * 4 + w;

    // stage z row (float4/lane); visible to other lanes after barrier #1
    *(float4*)&zrow_s[w][lane * 4] = *(const float4*)(z + (size_t)row * DIM + lane * 4);

    union { unsigned u; float f; } tv;
    tv.u = ((unsigned)tilemin_g[(size_t)row * 64 + lane]) << 16;
    const float tm = tv.f;
    float gmin = tm;
    #pragma unroll
    for (int d = 32; d > 0; d >>= 1) gmin = fminf(gmin, __shfl_xor(gmin, d, 64));
    const float thr = gmin + EPS;

    u64 m0 = 0, m1 = 0;
    if (tm <= thr) {
        const uchar_t* mb = mask_g + (size_t)row * 1024 + lane * 16;
        m0 = *(const u64*)(mb);
        m1 = *(const u64*)(mb + 8);
    }
    const unsigned cnt = __popcll(m0) + __popcll(m1);
    unsigned inc = cnt;
    #pragma unroll
    for (int d = 1; d < 64; d <<= 1) {
        const unsigned o = __shfl_up(inc, d, 64);
        if (lane >= d) inc += o;
    }
    const unsigned excl  = inc - cnt;
    const unsigned total = __shfl(inc, 63, 64);
    const float z2v = z2g[row];
    u64 best = ~0ull;

    __syncthreads();   // barrier #1: zrow_s visible (overflow eval below reads it)

    // emit candidates (bit p in m0/m1: byte c = p>>3, bit j = p&7 -> code j*16+c)
    unsigned slot = excl;
    while (m0) {
        const int p = __builtin_ctzll(m0); m0 &= m0 - 1;
        const unsigned code = lane * 128 + (p & 7) * 16 + (p >> 3);
        if (slot < CAND_CAP) cand_s[w][slot] = (ushort_t)code;
        else best = min(best, vq_eval(zrow_s[w], cb, e2g, z2v, (int)code));
        ++slot;
    }
    while (m1) {
        const int p = __builtin_ctzll(m1); m1 &= m1 - 1;
        const unsigned code = lane * 128 + (p & 7) * 16 + 8 + (p >> 3);
        if (slot < CAND_CAP) cand_s[w][slot] = (ushort_t)code;
        else best = min(best, vq_eval(zrow_s[w], cb, e2g, z2v, (int)code));
        ++slot;
    }

    __syncthreads();   // barrier #2: cand_s visible

    const int n = (int)(total < CAND_CAP ? total : CAND_CAP);
    for (int s = lane; s < n; s += 64)
        best = min(best, vq_eval(zrow_s[w], cb, e2g, z2v, (int)cand_s[w][s]));

    #pragma unroll
    for (int d = 32; d > 0; d >>= 1) {
        const u64 o = (u64)__shfl_xor((unsigned long long)best, d, 64);
        best = min(best, o);
    }
    if (lane == 0) {
        const int k = (int)(best & (u64)(NCODES - 1));
        idx_f[row] = (float)k;
        idx_i[row] = k;
    }
}

// ============================================================================
// Kernel D: gather + ST + loss. z_q_st = fl(z_e + fl(z_q - z_e)).
// ============================================================================
__global__ void vq_gather_loss_kernel(const float* __restrict__ z,
                                      const float* __restrict__ cb,
                                      const int* __restrict__ idx_i,
                                      float* __restrict__ zq_out,
                                      float* __restrict__ loss_acc) {
    const int lane = threadIdx.x & 63;
    const int wid  = threadIdx.x >> 6;
    const int row  = blockIdx.x * 4 + wid;
    const int k = idx_i[row];
    const float4 e  = *(const float4*)(cb + (size_t)k * DIM + lane * 4);
    const float4 zv = *(const float4*)(z + (size_t)row * DIM + lane * 4);
    const float dx = e.x - zv.x, dy = e.y - zv.y, dz = e.z - zv.z, dw = e.w - zv.w;
    float4 o;
    o.x = zv.x + dx; o.y = zv.y + dy; o.z = zv.z + dz; o.w = zv.w + dw;
    *(float4*)(zq_out + (size_t)row * DIM + lane * 4) = o;
    float s = dx * dx + dy * dy + dz * dz + dw * dw;
    #pragma unroll
    for (int off = 32; off > 0; off >>= 1) s += __shfl_down(s, off, 64);
    __shared__ float wsum[4];
    if (lane == 0) wsum[wid] = s;
    __syncthreads();
    if (threadIdx.x == 0)
        atomicAdd(loss_acc, wsum[0] + wsum[1] + wsum[2] + wsum[3]);
}

// ============================================================================
// Kernel E: finalize scalars.
// ============================================================================
__global__ void vq_finalize_kernel(const float* __restrict__ loss_acc,
                                   float* __restrict__ out_losses) {
    const float mean = *loss_acc * (1.0f / (float)(BATCH * DIM));  // /2^23 exact
    out_losses[0] = mean + BETA * mean;    // vq_loss
    out_losses[1] = mean;                  // cb_loss
    out_losses[2] = mean;                  // commit_loss
}

// ============================================================================
extern "C" void kernel_launch(void* const* d_in, const int* in_sizes, int n_in,
                              void* d_out, int out_size, void* d_ws, size_t ws_size,
                              hipStream_t stream) {
    const float* z  = (const float*)d_in[0];   // [32768, 256] fp32
    const float* cb = (const float*)d_in[1];   // [8192, 256]  fp32

    float* out    = (float*)d_out;
    float* zq     = out;                                   // [32768*256]
    float* idx_f  = out + (size_t)BATCH * DIM;             // [32768]
    float* losses = out + (size_t)BATCH * DIM + BATCH;     // [3]
    uchar_t* mask = (uchar_t*)d_out;                       // zq region reused: 1 KB/row

    // ws layout (~20.6 MB): ctrl[256 f] | e2 | z2 | tilemin(u16) | idxi(i32)
    //                       | zh(u16) | eh(u16)
    float*    ws        = (float*)d_ws;
    float*    loss_acc  = ws;                                       // [0]
    float*    e2        = ws + 256;                                 // 8192 f
    float*    z2        = e2 + NCODES;                              // 32768 f
    ushort_t* tilemin   = (ushort_t*)(z2 + BATCH);                  // 32768*64 u16
    int*      idxi      = (int*)(tilemin + (size_t)BATCH * 64);     // 32768 i32
    ushort_t* zh        = (ushort_t*)(idxi + BATCH);                // 32768*256 u16
    ushort_t* eh        = zh + (size_t)BATCH * DIM;                 // 8192*256 u16

    vq_prep_kernel<<<(NCODES + BATCH) / 4, 256, 0, stream>>>(z, cb, e2, z2, eh, zh, loss_acc);
    vq_screen_kernel<<<BATCH / 64, 256, 0, stream>>>(zh, eh, e2, tilemin, mask);
    vq_select_kernel<<<BATCH / 4, 256, 0, stream>>>(z, cb, e2, z2, tilemin, mask, idx_f, idxi);
    vq_gather_loss_kernel<<<BATCH / 4, 256, 0, stream>>>(z, cb, idxi, zq, loss_acc);
    vq_finalize_kernel<<<1, 1, 0, stream>>>(loss_acc, losses);
}

// Round 9
// 497.177 us; speedup vs baseline: 5.0034x; 1.0036x over previous
//
#include <hip/hip_runtime.h>

#define BATCH   32768
#define DIM     256
#define NCODES  8192
#define BETA    0.25f
#define EPS     3e-4f     // screen window: grid-tie ulp + 2*delta(bf16 screen) + bf16-tilemin fuzz
#define CAND_CAP 128      // per-row LDS candidate slots (avg ~16; overflow handled inline)

typedef unsigned short ushort_t;
typedef unsigned char  uchar_t;
typedef unsigned long long u64;
typedef __attribute__((ext_vector_type(8))) short bf16x8;
typedef __attribute__((ext_vector_type(4))) float f32x4;

// async global->LDS, 16B per lane; dest = wave-uniform base + lane*16
#define GLOAD16(gp, lp) __builtin_amdgcn_global_load_lds( \
    (const __attribute__((address_space(1))) void*)(gp), \
    (__attribute__((address_space(3))) void*)(lp), 16, 0, 0)

__device__ inline ushort_t f2bf(float f) {  // RNE float->bf16 (no NaN in data)
    union { float f; unsigned u; } v; v.f = f;
    return (ushort_t)((v.u + 0x7FFF + ((v.u >> 16) & 1)) >> 16);
}
__device__ inline ushort_t f2bf_rd(float f) {  // round toward -inf (conservative tilemin)
    union { float f; unsigned u; } v; v.f = f;
    unsigned u = v.u;
    if (f < 0.0f) u += 0xFFFFu;   // magnitude up for negatives => value down
    return (ushort_t)(u >> 16);
}

// ============================================================================
// Kernel A: fused prep. One wave per row (codebook rows then z rows):
// e2[k]/z2[b] row sums-of-squares + bf16 copies eh/zh. Zeroes the loss
// accumulator (d_ws is poisoned 0xAA every launch).
// ============================================================================
__global__ void vq_prep_kernel(const float* __restrict__ z,
                               const float* __restrict__ cb,
                               float* __restrict__ e2, float* __restrict__ z2,
                               ushort_t* __restrict__ eh, ushort_t* __restrict__ zh,
                               float* __restrict__ loss_acc) {
    const int lane = threadIdx.x & 63;
    const int wid  = threadIdx.x >> 6;
    const int item = blockIdx.x * 4 + wid;
    const float* src;
    ushort_t* dst;
    if (item < NCODES) { src = cb + (size_t)item * DIM;            dst = eh + (size_t)item * DIM; }
    else               { src = z  + (size_t)(item - NCODES) * DIM; dst = zh + (size_t)(item - NCODES) * DIM; }
    const float4 v = *(const float4*)(src + lane * 4);
    ushort4 b; b.x = f2bf(v.x); b.y = f2bf(v.y); b.z = f2bf(v.z); b.w = f2bf(v.w);
    *(ushort4*)(dst + lane * 4) = b;
    float s = v.x * v.x + v.y * v.y + v.z * v.z + v.w * v.w;
    #pragma unroll
    for (int off = 32; off > 0; off >>= 1) s += __shfl_down(s, off, 64);
    if (lane == 0) {
        if (item < NCODES) e2[item] = s;
        else               z2[item - NCODES] = s;
    }
    if (blockIdx.x == 0 && threadIdx.x == 0) *loss_acc = 0.0f;
}

// ============================================================================
// Kernel B: MFMA screen, 128 ROWS/BLOCK (8 waves, 512 thr) + DMA pipeline.
// R8 analysis: every 64-row block streamed all 4 MB of eh through L2 ->
// DMA 36 KB/chunk/block (~650 cyc) rivals the MFMA budget (621). Merging
// two row-halves into one block shares each eh staging across 128 rows:
// DMA/chunk = 8 KB zh + 32 KB eh for 2x the FLOP, and per-wave GLOADs drop
// 9 -> 5. Residency unchanged (256 regs/wave caps the CU at 8 waves
// regardless): grid 256 = 1 block/CU, LDS 80 KB dbuf.
// Pipeline: flat 128-chunk loop, one barrier per chunk, chunk n+1 staged
// right after barrier n before chunk n's MFMAs.
// Wave w: row-half h=w>>2 (64 rows), code-quarter cq=w&3 (128 codes).
// Outputs (bit-identical to R5-R8): bf16 round-down tile-min [row][tile]
// + 128-bit mask of codes with s <= tilemin_f32 + EPS (in d_out zq region).
// ============================================================================
__launch_bounds__(512, 2)
__global__ void vq_screen_kernel(const ushort_t* __restrict__ zh_g,
                                 const ushort_t* __restrict__ eh_g,
                                 const float* __restrict__ e2g,
                                 ushort_t* __restrict__ tilemin_g,
                                 uchar_t* __restrict__ mask_g) {
    __shared__ ushort_t zh_s[2][8 * 512];    // dbuf: 8 row-tiles of [16][32]
    __shared__ ushort_t eh_s[2][32 * 512];   // dbuf: 32 code-tiles of [16][32]

    const int t    = threadIdx.x;
    const int w    = t >> 6;        // wave 0..7
    const int lane = t & 63;
    const int c    = lane & 15;     // MFMA col / fragment row
    const int q    = lane >> 4;     // MFMA quad
    const int h    = w >> 2;        // row half (0: rows 0-63, 1: 64-127)
    const int cq   = w & 3;         // code quarter within the 512-code group
    const int row0 = blockIdx.x * 128;

    // stage chunk n (ct = n>>3, kc = (n&7)*32) into buffer b:
    // wave w stages zh row-tile w (1 KB) + eh tiles w*4..w*4+3 (4 KB)
    #define STAGE(n_, b_) do {                                                 \
        const int ct_ = (n_) >> 3;                                             \
        const int kc_ = ((n_) & 7) * 32;                                       \
        GLOAD16(zh_g + (size_t)(row0 + w * 16 + (lane >> 2)) * DIM + kc_ + (lane & 3) * 8, \
                &zh_s[b_][w * 512]);                                           \
        _Pragma("unroll")                                                      \
        for (int s_ = 0; s_ < 4; ++s_) {                                       \
            const int c16_ = w * 4 + s_;                                       \
            GLOAD16(eh_g + (size_t)(ct_ * 512 + c16_ * 16 + (lane >> 2)) * DIM + kc_ + (lane & 3) * 8, \
                    &eh_s[b_][c16_ * 512]);                                    \
        }                                                                      \
    } while (0)

    STAGE(0, 0);

    f32x4 acc[4][8];
    for (int n = 0; n < 128; ++n) {
        const int kc_i = n & 7;
        if (kc_i == 0) {
            #pragma unroll
            for (int i = 0; i < 4; ++i)
                #pragma unroll
                for (int j = 0; j < 8; ++j) acc[i][j] = (f32x4)0.0f;
        }
        __syncthreads();               // drains GLOADs (chunk n DMA complete)
        if (n < 127) STAGE(n + 1, (n + 1) & 1);
        const int b = n & 1;

        bf16x8 a[4], bfr[8];
        #pragma unroll
        for (int i = 0; i < 4; ++i)
            a[i] = *(const bf16x8*)&zh_s[b][(h * 4 + i) * 512 + c * 32 + q * 8];
        #pragma unroll
        for (int j = 0; j < 8; ++j)
            bfr[j] = *(const bf16x8*)&eh_s[b][(cq * 8 + j) * 512 + c * 32 + q * 8];
        #pragma unroll
        for (int i = 0; i < 4; ++i)
            #pragma unroll
            for (int j = 0; j < 8; ++j)
                acc[i][j] = __builtin_amdgcn_mfma_f32_16x16x32_bf16(a[i], bfr[j], acc[i][j], 0, 0, 0);

        if (kc_i == 7) {
            // epilogue for ct group: scores, per-row tile min, mask bits.
            const int ct = n >> 3;
            float e2v[8];
            #pragma unroll
            for (int j = 0; j < 8; ++j) e2v[j] = e2g[ct * 512 + cq * 128 + j * 16 + c];

            float tm[4][4];
            #pragma unroll
            for (int i = 0; i < 4; ++i)
                #pragma unroll
                for (int reg = 0; reg < 4; ++reg) tm[i][reg] = 3.4e38f;
            #pragma unroll
            for (int i = 0; i < 4; ++i)
                #pragma unroll
                for (int j = 0; j < 8; ++j)
                    #pragma unroll
                    for (int reg = 0; reg < 4; ++reg) {
                        const float s = fmaf(-2.0f, acc[i][j][reg], e2v[j]);
                        acc[i][j][reg] = s;
                        tm[i][reg] = fminf(tm[i][reg], s);
                    }
            #pragma unroll
            for (int st = 1; st < 16; st <<= 1)
                #pragma unroll
                for (int i = 0; i < 4; ++i)
                    #pragma unroll
                    for (int reg = 0; reg < 4; ++reg)
                        tm[i][reg] = fminf(tm[i][reg], __shfl_xor(tm[i][reg], st, 64));

            const int tile = ct * 4 + cq;
            #pragma unroll
            for (int i = 0; i < 4; ++i)
                #pragma unroll
                for (int reg = 0; reg < 4; ++reg) {
                    const int row = row0 + h * 64 + i * 16 + q * 4 + reg;
                    const float thr = tm[i][reg] + EPS;
                    unsigned m8 = 0;
                    #pragma unroll
                    for (int j = 0; j < 8; ++j)
                        m8 |= (unsigned)(acc[i][j][reg] <= thr) << j;
                    mask_g[(size_t)row * 1024 + tile * 16 + c] = (uchar_t)m8;
                    if (c == 0) tilemin_g[(size_t)row * 64 + tile] = f2bf_rd(tm[i][reg]);
                }
        }
    }
    #undef STAGE
}

// ============================================================================
// exact score, bit-identical to R2's verified numerics: ascending-k
// sequential fmaf; S = fl(z2+e2); score = fl(S - 2*acc). Returns
// (score_bits<<32 | code): positive scores => float bits monotone; u64 min
// over candidates => lowest code on exact grid ties.
// ============================================================================
__device__ inline u64 vq_eval(const float* zrow, const float* __restrict__ cb,
                              const float* __restrict__ e2g, float z2v, int code) {
    const float4* z4 = (const float4*)zrow;
    const float4* e4 = (const float4*)(cb + (size_t)code * DIM);
    float acc = 0.0f;
    #pragma unroll 8
    for (int k4 = 0; k4 < DIM / 4; ++k4) {
        const float4 a = z4[k4];
        const float4 b = e4[k4];
        acc = fmaf(a.x, b.x, acc);
        acc = fmaf(a.y, b.y, acc);
        acc = fmaf(a.z, b.z, acc);
        acc = fmaf(a.w, b.w, acc);
    }
    const float S  = z2v + e2g[code];
    const float sc = fmaf(-2.0f, acc, S);
    union { float f; unsigned u; } sb; sb.f = sc;
    return ((u64)sb.u << 32) | (unsigned)code;
}

// ============================================================================
// Kernel C: fused select (no global atomics, no worklist round-trip).
// ONE WAVE PER ROW (lane = tile): coalesced bf16 tile-min load, butterfly
// gmin, active lanes enumerate their tile's mask into per-wave LDS slots
// via prefix scan; then lane = slot evaluates exact scores (z row
// LDS-cached); in-wave u64 butterfly min picks the winner. >CAND_CAP
// overflow evaluated inline by the emitting lane (min is associative).
// ============================================================================
__global__ void vq_select_kernel(const float* __restrict__ z,
                                 const float* __restrict__ cb,
                                 const float* __restrict__ e2g,
                                 const float* __restrict__ z2g,
                                 const ushort_t* __restrict__ tilemin_g,
                                 const uchar_t* __restrict__ mask_g,
                                 float* __restrict__ idx_f,
                                 int* __restrict__ idx_i) {
    __shared__ float    zrow_s[4][DIM];
    __shared__ ushort_t cand_s[4][CAND_CAP];

    const int lane = threadIdx.x & 63;
    const int w    = threadIdx.x >> 6;
    const int row  = blockIdx.x * 4 + w;

    // stage z row (float4/lane); visible to other lanes after barrier #1
    *(float4*)&zrow_s[w][lane * 4] = *(const float4*)(z + (size_t)row * DIM + lane * 4);

    union { unsigned u; float f; } tv;
    tv.u = ((unsigned)tilemin_g[(size_t)row * 64 + lane]) << 16;
    const float tm = tv.f;
    float gmin = tm;
    #pragma unroll
    for (int d = 32; d > 0; d >>= 1) gmin = fminf(gmin, __shfl_xor(gmin, d, 64));
    const float thr = gmin + EPS;

    u64 m0 = 0, m1 = 0;
    if (tm <= thr) {
        const uchar_t* mb = mask_g + (size_t)row * 1024 + lane * 16;
        m0 = *(const u64*)(mb);
        m1 = *(const u64*)(mb + 8);
    }
    const unsigned cnt = __popcll(m0) + __popcll(m1);
    unsigned inc = cnt;
    #pragma unroll
    for (int d = 1; d < 64; d <<= 1) {
        const unsigned o = __shfl_up(inc, d, 64);
        if (lane >= d) inc += o;
    }
    const unsigned excl  = inc - cnt;
    const unsigned total = __shfl(inc, 63, 64);
    const float z2v = z2g[row];
    u64 best = ~0ull;

    __syncthreads();   // barrier #1: zrow_s visible (overflow eval below reads it)

    // emit candidates (bit p in m0/m1: byte c = p>>3, bit j = p&7 -> code j*16+c)
    unsigned slot = excl;
    while (m0) {
        const int p = __builtin_ctzll(m0); m0 &= m0 - 1;
        const unsigned code = lane * 128 + (p & 7) * 16 + (p >> 3);
        if (slot < CAND_CAP) cand_s[w][slot] = (ushort_t)code;
        else best = min(best, vq_eval(zrow_s[w], cb, e2g, z2v, (int)code));
        ++slot;
    }
    while (m1) {
        const int p = __builtin_ctzll(m1); m1 &= m1 - 1;
        const unsigned code = lane * 128 + (p & 7) * 16 + 8 + (p >> 3);
        if (slot < CAND_CAP) cand_s[w][slot] = (ushort_t)code;
        else best = min(best, vq_eval(zrow_s[w], cb, e2g, z2v, (int)code));
        ++slot;
    }

    __syncthreads();   // barrier #2: cand_s visible

    const int n = (int)(total < CAND_CAP ? total : CAND_CAP);
    for (int s = lane; s < n; s += 64)
        best = min(best, vq_eval(zrow_s[w], cb, e2g, z2v, (int)cand_s[w][s]));

    #pragma unroll
    for (int d = 32; d > 0; d >>= 1) {
        const u64 o = (u64)__shfl_xor((unsigned long long)best, d, 64);
        best = min(best, o);
    }
    if (lane == 0) {
        const int k = (int)(best & (u64)(NCODES - 1));
        idx_f[row] = (float)k;
        idx_i[row] = k;
    }
}

// ============================================================================
// Kernel D: gather + ST + loss. z_q_st = fl(z_e + fl(z_q - z_e)).
// ============================================================================
__global__ void vq_gather_loss_kernel(const float* __restrict__ z,
                                      const float* __restrict__ cb,
                                      const int* __restrict__ idx_i,
                                      float* __restrict__ zq_out,
                                      float* __restrict__ loss_acc) {
    const int lane = threadIdx.x & 63;
    const int wid  = threadIdx.x >> 6;
    const int row  = blockIdx.x * 4 + wid;
    const int k = idx_i[row];
    const float4 e  = *(const float4*)(cb + (size_t)k * DIM + lane * 4);
    const float4 zv = *(const float4*)(z + (size_t)row * DIM + lane * 4);
    const float dx = e.x - zv.x, dy = e.y - zv.y, dz = e.z - zv.z, dw = e.w - zv.w;
    float4 o;
    o.x = zv.x + dx; o.y = zv.y + dy; o.z = zv.z + dz; o.w = zv.w + dw;
    *(float4*)(zq_out + (size_t)row * DIM + lane * 4) = o;
    float s = dx * dx + dy * dy + dz * dz + dw * dw;
    #pragma unroll
    for (int off = 32; off > 0; off >>= 1) s += __shfl_down(s, off, 64);
    __shared__ float wsum[4];
    if (lane == 0) wsum[wid] = s;
    __syncthreads();
    if (threadIdx.x == 0)
        atomicAdd(loss_acc, wsum[0] + wsum[1] + wsum[2] + wsum[3]);
}

// ============================================================================
// Kernel E: finalize scalars.
// ============================================================================
__global__ void vq_finalize_kernel(const float* __restrict__ loss_acc,
                                   float* __restrict__ out_losses) {
    const float mean = *loss_acc * (1.0f / (float)(BATCH * DIM));  // /2^23 exact
    out_losses[0] = mean + BETA * mean;    // vq_loss
    out_losses[1] = mean;                  // cb_loss
    out_losses[2] = mean;                  // commit_loss
}

// ============================================================================
extern "C" void kernel_launch(void* const* d_in, const int* in_sizes, int n_in,
                              void* d_out, int out_size, void* d_ws, size_t ws_size,
                              hipStream_t stream) {
    const float* z  = (const float*)d_in[0];   // [32768, 256] fp32
    const float* cb = (const float*)d_in[1];   // [8192, 256]  fp32

    float* out    = (float*)d_out;
    float* zq     = out;                                   // [32768*256]
    float* idx_f  = out + (size_t)BATCH * DIM;             // [32768]
    float* losses = out + (size_t)BATCH * DIM + BATCH;     // [3]
    uchar_t* mask = (uchar_t*)d_out;                       // zq region reused: 1 KB/row

    // ws layout (~20.6 MB): ctrl[256 f] | e2 | z2 | tilemin(u16) | idxi(i32)
    //                       | zh(u16) | eh(u16)
    float*    ws        = (float*)d_ws;
    float*    loss_acc  = ws;                                       // [0]
    float*    e2        = ws + 256;                                 // 8192 f
    float*    z2        = e2 + NCODES;                              // 32768 f
    ushort_t* tilemin   = (ushort_t*)(z2 + BATCH);                  // 32768*64 u16
    int*      idxi      = (int*)(tilemin + (size_t)BATCH * 64);     // 32768 i32
    ushort_t* zh        = (ushort_t*)(idxi + BATCH);                // 32768*256 u16
    ushort_t* eh        = zh + (size_t)BATCH * DIM;                 // 8192*256 u16

    vq_prep_kernel<<<(NCODES + BATCH) / 4, 256, 0, stream>>>(z, cb, e2, z2, eh, zh, loss_acc);
    vq_screen_kernel<<<BATCH / 128, 512, 0, stream>>>(zh, eh, e2, tilemin, mask);
    vq_select_kernel<<<BATCH / 4, 256, 0, stream>>>(z, cb, e2, z2, tilemin, mask, idx_f, idxi);
    vq_gather_loss_kernel<<<BATCH / 4, 256, 0, stream>>>(z, cb, idxi, zq, loss_acc);
    vq_finalize_kernel<<<1, 1, 0, stream>>>(loss_acc, losses);
}